// Round 7
// baseline (34.496 us; speedup 1.0000x reference)
//
#include <hip/hip_runtime.h>
#include <hip/hip_bf16.h>
#include <math.h>

#define N_ATOMS 1024
#define IN_F 64
#define H_DIM 32
#define NRBF 50
#define TILE 16
#define NT 64
#define NBT 2080
#define TBL 4096

typedef short bf16x8 __attribute__((ext_vector_type(8)));
typedef float f32x4  __attribute__((ext_vector_type(4)));

static __device__ __forceinline__ unsigned short f2bf(float f) {
    unsigned int u = __float_as_uint(f);
    u += 0x7fffu + ((u >> 16) & 1u);     // RNE (prep only)
    return (unsigned short)(u >> 16);
}

// ---- Kernel 1: hp = h@W_fc, f32 G table, W1 fragments, bw, tile table ------
__global__ __launch_bounds__(256) void prep_kernel(
    const float* __restrict__ h, const float* __restrict__ W_fc,
    const float* __restrict__ W_edge, const float* __restrict__ means,
    const float* __restrict__ betas, const float* __restrict__ W1,
    const float* __restrict__ b1, const float* __restrict__ W2,
    float* __restrict__ hp, float* __restrict__ Gf,
    unsigned short* __restrict__ Wp, float2* __restrict__ bw,
    int* __restrict__ tt)
{
    const int blk = blockIdx.x;
    const int t = threadIdx.x;
    if (blk < 128) {                       // hp
        int id = blk * 256 + t;
        int i = id >> 5, o = id & 31;
        float acc = 0.f;
        #pragma unroll 8
        for (int k = 0; k < IN_F; ++k)
            acc += h[i * IN_F + k] * W_fc[k * H_DIM + o];
        hp[i * H_DIM + o] = acc;
    } else if (blk < 192) {                // G table (f32)
        int id = (blk - 128) * 256 + t;
        int idx = id >> 2, c0 = (id & 3) * 8;
        float ed = (float)idx * (1.0f / (float)(TBL - 1));
        float acc[8];
        #pragma unroll
        for (int c = 0; c < 8; ++c) acc[c] = 0.f;
        for (int k = 0; k < NRBF; ++k) {   // uniform -> scalar loads
            float d = ed - means[k];
            float wv = __expf(-betas[k] * d * d);
            #pragma unroll
            for (int c = 0; c < 8; ++c)
                acc[c] += wv * W_edge[k * H_DIM + c0 + c];
        }
        #pragma unroll
        for (int c = 0; c < 8; ++c) Gf[idx * H_DIM + c0 + c] = acc[c];
    } else if (blk < 201) {                // triangular tile table
        int e = (blk - 192) * 256 + t;
        if (e < NBT) {
            int ti = (int)(64.5f - sqrtf(64.5f * 64.5f - 2.0f * (float)e));
            ti = ti < 0 ? 0 : (ti > NT - 1 ? NT - 1 : ti);
            while ((ti + 1) * NT - ((ti + 1) * ti) / 2 <= e) ++ti;
            while (ti > 0 && ti * NT - (ti * (ti - 1)) / 2 > e) --ti;
            int tj = ti + (e - (ti * NT - (ti * (ti - 1)) / 2));
            tt[e] = (ti << 8) | tj;
        }
    } else {                               // W1 fragments + bw
        #pragma unroll
        for (int q = 0; q < 4; ++q) {
            int f  = t * 4 + q;            // f = ct*512 + lane*8 + j
            int ct = f >> 9, ln = (f >> 3) & 63, j = f & 7;
            int c0f = ln & 15, kb = (ln >> 4) * 8;
            Wp[f] = f2bf(W1[(kb + j) * H_DIM + c0f + 16 * ct]);
        }
        if (t < 32) { float2 v; v.x = b1[t]; v.y = W2[t]; bw[t] = v; }
    }
}

// ---- Kernel 2: barrier-free fragment-direct pair kernel --------------------
// Wave w, subtile rt, lane (c0f = lane&15, kb = (lane>>4)*8) owns
// pair (i = i0 + w*4 + rt, j = j0 + c0f), features kb..kb+7 == the exact
// MFMA A-fragment element set. No LDS transpose, no barriers before reduce.
__global__ __launch_bounds__(256, 8) void pair_kernel(
    const float* __restrict__ x, const float* __restrict__ hp,
    const float* __restrict__ Gf, const unsigned short* __restrict__ Wp,
    const float2* __restrict__ bw, const int* __restrict__ tt,
    float* __restrict__ partials)
{
    __shared__ float swave[4];

    const int t    = threadIdx.x;
    const int lane = t & 63;
    const int w    = t >> 6;
    const int c0f  = lane & 15;
    const int kb   = (lane >> 4) * 8;
    const int b    = blockIdx.x;

    const int tv = tt[b];                  // uniform -> s_load
    const int ti = tv >> 8, tj = tv & 255;
    const int i0 = ti * TILE, j0 = tj * TILE;
    const float wgt = (ti == tj) ? 1.0f : 2.0f;

    // hoisted per-thread invariants (j-side), issue early
    const float4 hja = *(const float4*)&hp[(j0 + c0f) * H_DIM + kb];
    const float4 hjb = *(const float4*)&hp[(j0 + c0f) * H_DIM + kb + 4];
    const float xj0 = x[(j0 + c0f) * 3 + 0];
    const float xj1 = x[(j0 + c0f) * 3 + 1];
    const float xj2 = x[(j0 + c0f) * 3 + 2];

    // pre-packed W1 fragments + bias/W2 columns
    const bf16x8 bfrag0 = *(const bf16x8*)&Wp[lane * 8];
    const bf16x8 bfrag1 = *(const bf16x8*)&Wp[512 + lane * 8];
    const float2 bw0 = bw[c0f];
    const float2 bw1 = bw[c0f + 16];

    float p = 0.f;

    #pragma unroll
    for (int rt = 0; rt < 4; ++rt) {
        const int ri = w * 4 + rt;                     // wave-uniform i row
        // i-side coords/features: same address across lanes -> broadcast
        const float xi0 = x[(i0 + ri) * 3 + 0];
        const float xi1 = x[(i0 + ri) * 3 + 1];
        const float xi2 = x[(i0 + ri) * 3 + 2];

        const float dx = xj0 - xi0, dy = xj1 - xi1, dz = xj2 - xi2;
        const float s  = dx * dx + dy * dy + dz * dz;
        const float dist = s + 1e-8f;
        const float dn2  = s / (s + 1e-8f);            // exactly 0 on diagonal
        const float sn   = __sinf(0.62831853f * dist);
        const float K    = dn2 * (sn * sn) * (sn * sn);
        const float ed   = __expf(-dist);

        float uu = ed * (float)(TBL - 1);
        int idx  = (int)(uu + 0.5f);
        if (idx > TBL - 1) idx = TBL - 1;

        const float* __restrict__ gp = Gf + idx * H_DIM + kb;
        const float4 ga = *(const float4*)gp;
        const float4 gb = *(const float4*)(gp + 4);

        const float4 hia = *(const float4*)&hp[(i0 + ri) * H_DIM + kb];
        const float4 hib = *(const float4*)&hp[(i0 + ri) * H_DIM + kb + 4];

        const float v0 = (hia.x + hja.x) * ga.x;
        const float v1 = (hia.y + hja.y) * ga.y;
        const float v2 = (hia.z + hja.z) * ga.z;
        const float v3 = (hia.w + hja.w) * ga.w;
        const float v4 = (hib.x + hjb.x) * gb.x;
        const float v5 = (hib.y + hjb.y) * gb.y;
        const float v6 = (hib.z + hjb.z) * gb.z;
        const float v7 = (hib.w + hjb.w) * gb.w;
        const float c0 = v0 * v0 * K, c1 = v1 * v1 * K;
        const float c2 = v2 * v2 * K, c3 = v3 * v3 * K;
        const float c4 = v4 * v4 * K, c5 = v5 * v5 * K;
        const float c6 = v6 * v6 * K, c7 = v7 * v7 * K;

        union { bf16x8 v8; unsigned int u[4]; } pk;    // round-half-up pack
        pk.u[0] = ((__float_as_uint(c0) + 0x8000u) >> 16) | ((__float_as_uint(c1) + 0x8000u) & 0xffff0000u);
        pk.u[1] = ((__float_as_uint(c2) + 0x8000u) >> 16) | ((__float_as_uint(c3) + 0x8000u) & 0xffff0000u);
        pk.u[2] = ((__float_as_uint(c4) + 0x8000u) >> 16) | ((__float_as_uint(c5) + 0x8000u) & 0xffff0000u);
        pk.u[3] = ((__float_as_uint(c6) + 0x8000u) >> 16) | ((__float_as_uint(c7) + 0x8000u) & 0xffff0000u);

        f32x4 acc0 = {0.f, 0.f, 0.f, 0.f};
        acc0 = __builtin_amdgcn_mfma_f32_16x16x32_bf16(pk.v8, bfrag0, acc0, 0, 0, 0);
        f32x4 acc1 = {0.f, 0.f, 0.f, 0.f};
        acc1 = __builtin_amdgcn_mfma_f32_16x16x32_bf16(pk.v8, bfrag1, acc1, 0, 0, 0);

        #pragma unroll
        for (int r = 0; r < 4; ++r) {
            const float av0 = acc0[r] + bw0.x;
            p += bw0.y * __builtin_amdgcn_rcpf(1.0f + __expf(-av0));
            const float av1 = acc1[r] + bw1.x;
            p += bw1.y * __builtin_amdgcn_rcpf(1.0f + __expf(-av1));
        }
    }

    // block reduction (deterministic)
    float v = wgt * p;
    #pragma unroll
    for (int off = 32; off > 0; off >>= 1)
        v += __shfl_down(v, off);
    if (lane == 0) swave[w] = v;
    __syncthreads();
    if (t == 0)
        partials[b] = (swave[0] + swave[1]) + (swave[2] + swave[3]);
}

// ---- Kernel 3: final deterministic reduction -------------------------------
__global__ __launch_bounds__(256) void reduce_kernel(
    const float* __restrict__ partials, const float* __restrict__ b2,
    float* __restrict__ out)
{
    __shared__ float sm[256];
    const int t = threadIdx.x;
    float a = 0.f;
    for (int u = t; u < NBT; u += 256) a += partials[u];
    sm[t] = a;
    __syncthreads();
    for (int off = 128; off > 0; off >>= 1) {
        if (t < off) sm[t] += sm[t + off];
        __syncthreads();
    }
    if (t == 0)
        out[0] = sm[0] + (float)N_ATOMS * (float)N_ATOMS * b2[0];
}

extern "C" void kernel_launch(void* const* d_in, const int* in_sizes, int n_in,
                              void* d_out, int out_size, void* d_ws, size_t ws_size,
                              hipStream_t stream) {
    const float* h      = (const float*)d_in[0];
    const float* x      = (const float*)d_in[1];
    const float* W_fc   = (const float*)d_in[2];
    const float* W_edge = (const float*)d_in[3];
    const float* means  = (const float*)d_in[4];
    const float* betas  = (const float*)d_in[5];
    const float* W1     = (const float*)d_in[6];
    const float* b1     = (const float*)d_in[7];
    const float* W2     = (const float*)d_in[8];
    const float* b2     = (const float*)d_in[9];
    float* out = (float*)d_out;

    char* base = (char*)d_ws;
    float*          ws_partials = (float*)base;                    // 2560 f @0
    float*          ws_hp       = (float*)(base + 10240);          // 32768 f
    float*          ws_Gf       = (float*)(base + 141312);         // 4096*32 f
    unsigned short* ws_Wp       = (unsigned short*)(base + 665600);// 1024 bf16
    float2*         ws_bw       = (float2*)(base + 667648);        // 32 float2
    int*            ws_tt       = (int*)(base + 667904);           // 2080 int

    prep_kernel<<<202, 256, 0, stream>>>(h, W_fc, W_edge, means, betas,
                                         W1, b1, W2, ws_hp, ws_Gf, ws_Wp,
                                         ws_bw, ws_tt);
    pair_kernel<<<NBT, 256, 0, stream>>>(x, ws_hp, ws_Gf, ws_Wp, ws_bw,
                                         ws_tt, ws_partials);
    reduce_kernel<<<1, 256, 0, stream>>>(ws_partials, b2, out);
}

// Round 8
// 24.639 us; speedup vs baseline: 1.4000x; 1.4000x over previous
//
#include <hip/hip_runtime.h>
#include <hip/hip_bf16.h>
#include <math.h>

#define N_ATOMS 1024
#define IN_F 64
#define H_DIM 32
#define NRBF 50
#define TILE 16
#define NT 64
#define NBLK 1056             // Σ_ti (32 - ti/2)
#define TBL 4096
#define SASTR 40              // LDS A row stride (bf16 elems), 80B rows

typedef short bf16x8 __attribute__((ext_vector_type(8)));
typedef float f32x4  __attribute__((ext_vector_type(4)));

static __device__ __forceinline__ unsigned short f2bf(float f) {
    unsigned int u = __float_as_uint(f);
    u += 0x7fffu + ((u >> 16) & 1u);     // RNE (prep only)
    return (unsigned short)(u >> 16);
}

// ---- Kernel 1: hp = h@W_fc, bf16 G table, W1 fragments, bw, tile table -----
__global__ __launch_bounds__(256) void prep_kernel(
    const float* __restrict__ h, const float* __restrict__ W_fc,
    const float* __restrict__ W_edge, const float* __restrict__ means,
    const float* __restrict__ betas, const float* __restrict__ W1,
    const float* __restrict__ b1, const float* __restrict__ W2,
    float* __restrict__ hp, unsigned short* __restrict__ Gb,
    unsigned short* __restrict__ Wp, float2* __restrict__ bw,
    int* __restrict__ tt)
{
    const int blk = blockIdx.x;
    const int t = threadIdx.x;
    if (blk < 128) {                       // hp
        int id = blk * 256 + t;
        int i = id >> 5, o = id & 31;
        float acc = 0.f;
        #pragma unroll 8
        for (int k = 0; k < IN_F; ++k)
            acc += h[i * IN_F + k] * W_fc[k * H_DIM + o];
        hp[i * H_DIM + o] = acc;
    } else if (blk < 192) {                // G table (bf16, nearest-neighbor)
        int id = (blk - 128) * 256 + t;
        int idx = id >> 2, c0 = (id & 3) * 8;
        float ed = (float)idx * (1.0f / (float)(TBL - 1));
        float acc[8];
        #pragma unroll
        for (int c = 0; c < 8; ++c) acc[c] = 0.f;
        for (int k = 0; k < NRBF; ++k) {   // uniform -> scalar loads
            float d = ed - means[k];
            float wv = __expf(-betas[k] * d * d);
            #pragma unroll
            for (int c = 0; c < 8; ++c)
                acc[c] += wv * W_edge[k * H_DIM + c0 + c];
        }
        bf16x8 pk;
        #pragma unroll
        for (int c = 0; c < 8; ++c) pk[c] = (short)f2bf(acc[c]);
        *(bf16x8*)&Gb[idx * H_DIM + c0] = pk;
    } else if (blk < 197) {                // (ti, tj2) block table, 1056 entries
        int e = (blk - 192) * 256 + t;
        if (e < NBLK) {
            // row ti=2a+b has length 32-a, offset(2a)=a*(65-a)
            int a = (int)((65.0f - sqrtf(65.0f * 65.0f - 4.0f * (float)e)) * 0.5f);
            a = a < 0 ? 0 : (a > 31 ? 31 : a);
            while (a > 0 && a * (65 - a) > e) --a;
            while ((a + 1) * (65 - (a + 1)) <= e) ++a;
            int e1 = e - a * (65 - a);
            int ti, tj2;
            if (e1 < 32 - a) { ti = 2 * a;     tj2 = a + e1; }
            else             { ti = 2 * a + 1; tj2 = a + e1 - (32 - a); }
            tt[e] = (ti << 8) | tj2;
        }
    } else {                               // W1 fragments + bw
        #pragma unroll
        for (int q = 0; q < 4; ++q) {
            int f  = t * 4 + q;            // f = ct*512 + lane*8 + j
            int ct = f >> 9, ln = (f >> 3) & 63, j = f & 7;
            int c0f = ln & 15, kb = (ln >> 4) * 8;
            Wp[f] = f2bf(W1[(kb + j) * H_DIM + c0f + 16 * ct]);
        }
        if (t < 32) { float2 v; v.x = b1[t]; v.y = W2[t]; bw[t] = v; }
    }
}

// ---- Kernel 2: 16x32 pair block (two 16x16 phases sharing sA) --------------
__global__ __launch_bounds__(256, 5) void pair_kernel(
    const float* __restrict__ x, const float* __restrict__ hp,
    const unsigned short* __restrict__ Gb, const unsigned short* __restrict__ Wp,
    const float2* __restrict__ bw, const int* __restrict__ tt,
    float* __restrict__ partials)
{
    __shared__ float shpi[TILE][36], shpjA[TILE][36], shpjB[TILE][36];
    __shared__ unsigned short sA[256 * SASTR];
    __shared__ float swave[4];

    const int t    = threadIdx.x;
    const int lane = t & 63;
    const int w    = t >> 6;
    const int c0f  = lane & 15;
    const int b    = blockIdx.x;

    const int tv  = tt[b];                 // uniform -> s_load
    const int ti  = tv >> 8, tj2 = tv & 255;
    const int i0  = ti * TILE;
    const int j0A = tj2 * 32, j0B = j0A + 16;
    const int tjA = 2 * tj2, tjB = tjA + 1;
    const float wgtA = (tjA < ti) ? 0.f : (tjA == ti ? 1.f : 2.f);
    const float wgtB = (tjB == ti) ? 1.f : 2.f;

    const int li = t >> 4;
    const int lj = t & 15;

    // x coords direct from global (L1-hot)
    const float xi0 = x[(i0 + li) * 3 + 0];
    const float xi1 = x[(i0 + li) * 3 + 1];
    const float xi2 = x[(i0 + li) * 3 + 2];
    const float xA0 = x[(j0A + lj) * 3 + 0];
    const float xA1 = x[(j0A + lj) * 3 + 1];
    const float xA2 = x[(j0A + lj) * 3 + 2];
    const float xB0 = x[(j0B + lj) * 3 + 0];
    const float xB1 = x[(j0B + lj) * 3 + 1];
    const float xB2 = x[(j0B + lj) * 3 + 2];

    // stage hp tiles: 1-2 float4 per thread
    if (t < 128) {
        int r = t >> 3, c = t & 7;
        *(float4*)&shpi[r][c * 4]  = *(const float4*)&hp[(i0 + r) * H_DIM + c * 4];
        *(float4*)&shpjB[r][c * 4] = *(const float4*)&hp[(j0B + r) * H_DIM + c * 4];
    } else {
        int u = t - 128, r = u >> 3, c = u & 7;
        *(float4*)&shpjA[r][c * 4] = *(const float4*)&hp[(j0A + r) * H_DIM + c * 4];
    }

    // pre-packed W1 fragments + bias/W2 columns
    const bf16x8 bfrag0 = *(const bf16x8*)&Wp[lane * 8];
    const bf16x8 bfrag1 = *(const bf16x8*)&Wp[512 + lane * 8];
    const float2 bw0 = bw[c0f];
    const float2 bw1 = bw[c0f + 16];

    // ---- scalars for BOTH phases; issue both gathers before first barrier --
    float dx = xA0 - xi0, dy = xA1 - xi1, dz = xA2 - xi2;
    float sA_ = dx * dx + dy * dy + dz * dz;
    const float distA = sA_ + 1e-8f;
    const float dn2A  = sA_ / (sA_ + 1e-8f);
    const float snA   = __sinf(0.62831853f * distA);
    const float KA    = dn2A * (snA * snA) * (snA * snA);
    const float edA   = __expf(-distA);
    float uuA = edA * (float)(TBL - 1);
    int idxA  = (int)(uuA + 0.5f);
    if (idxA > TBL - 1) idxA = TBL - 1;
    const unsigned short* __restrict__ rA = Gb + idxA * H_DIM;
    const bf16x8 gA0 = *(const bf16x8*)(rA);
    const bf16x8 gA1 = *(const bf16x8*)(rA + 8);
    const bf16x8 gA2 = *(const bf16x8*)(rA + 16);
    const bf16x8 gA3 = *(const bf16x8*)(rA + 24);

    dx = xB0 - xi0; dy = xB1 - xi1; dz = xB2 - xi2;
    float sB_ = dx * dx + dy * dy + dz * dz;
    const float distB = sB_ + 1e-8f;
    const float dn2B  = sB_ / (sB_ + 1e-8f);
    const float snB   = __sinf(0.62831853f * distB);
    const float KB    = dn2B * (snB * snB) * (snB * snB);
    const float edB   = __expf(-distB);
    float uuB = edB * (float)(TBL - 1);
    int idxB  = (int)(uuB + 0.5f);
    if (idxB > TBL - 1) idxB = TBL - 1;
    const unsigned short* __restrict__ rB = Gb + idxB * H_DIM;
    const bf16x8 gB0 = *(const bf16x8*)(rB);
    const bf16x8 gB1 = *(const bf16x8*)(rB + 8);
    const bf16x8 gB2 = *(const bf16x8*)(rB + 16);
    const bf16x8 gB3 = *(const bf16x8*)(rB + 24);

    __syncthreads();                       // hp tiles visible

    const int sw = (t >> 3) & 3;
    float p = 0.f;

    // =================== PHASE A (skippable, block-uniform) =================
    if (wgtA != 0.f) {
        #pragma unroll
        for (int q = 0; q < 4; ++q) {
            const bf16x8 gs = (q == 0) ? gA0 : (q == 1) ? gA1 : (q == 2) ? gA2 : gA3;
            union { bf16x8 v8; unsigned int u[4]; } gu, pk;
            gu.v8 = gs;
            const float4 hi0 = *(const float4*)&shpi[li][q * 8];
            const float4 hi1 = *(const float4*)&shpi[li][q * 8 + 4];
            const float4 hj0 = *(const float4*)&shpjA[lj][q * 8];
            const float4 hj1 = *(const float4*)&shpjA[lj][q * 8 + 4];
            float g0 = __uint_as_float(gu.u[0] << 16);
            float g1 = __uint_as_float(gu.u[0] & 0xffff0000u);
            float g2 = __uint_as_float(gu.u[1] << 16);
            float g3 = __uint_as_float(gu.u[1] & 0xffff0000u);
            float g4 = __uint_as_float(gu.u[2] << 16);
            float g5 = __uint_as_float(gu.u[2] & 0xffff0000u);
            float g6 = __uint_as_float(gu.u[3] << 16);
            float g7 = __uint_as_float(gu.u[3] & 0xffff0000u);
            float v0 = (hi0.x + hj0.x) * g0, v1 = (hi0.y + hj0.y) * g1;
            float v2 = (hi0.z + hj0.z) * g2, v3 = (hi0.w + hj0.w) * g3;
            float v4 = (hi1.x + hj1.x) * g4, v5 = (hi1.y + hj1.y) * g5;
            float v6 = (hi1.z + hj1.z) * g6, v7 = (hi1.w + hj1.w) * g7;
            float c0 = v0 * v0 * KA, c1 = v1 * v1 * KA, c2 = v2 * v2 * KA, c3 = v3 * v3 * KA;
            float c4 = v4 * v4 * KA, c5 = v5 * v5 * KA, c6 = v6 * v6 * KA, c7 = v7 * v7 * KA;
            pk.u[0] = ((__float_as_uint(c0) + 0x8000u) >> 16) | ((__float_as_uint(c1) + 0x8000u) & 0xffff0000u);
            pk.u[1] = ((__float_as_uint(c2) + 0x8000u) >> 16) | ((__float_as_uint(c3) + 0x8000u) & 0xffff0000u);
            pk.u[2] = ((__float_as_uint(c4) + 0x8000u) >> 16) | ((__float_as_uint(c5) + 0x8000u) & 0xffff0000u);
            pk.u[3] = ((__float_as_uint(c6) + 0x8000u) >> 16) | ((__float_as_uint(c7) + 0x8000u) & 0xffff0000u);
            *(bf16x8*)&sA[t * SASTR + (q ^ sw) * 8] = pk.v8;
        }
        __syncthreads();

        float pA = 0.f;
        #pragma unroll
        for (int rt = 0; rt < 4; ++rt) {
            const int row = w * 64 + rt * 16 + c0f;
            const int rq  = (lane >> 4) ^ ((row >> 3) & 3);
            bf16x8 afrag = *(const bf16x8*)&sA[row * SASTR + rq * 8];
            f32x4 acc0 = {0.f, 0.f, 0.f, 0.f};
            acc0 = __builtin_amdgcn_mfma_f32_16x16x32_bf16(afrag, bfrag0, acc0, 0, 0, 0);
            f32x4 acc1 = {0.f, 0.f, 0.f, 0.f};
            acc1 = __builtin_amdgcn_mfma_f32_16x16x32_bf16(afrag, bfrag1, acc1, 0, 0, 0);
            #pragma unroll
            for (int r = 0; r < 4; ++r) {
                pA += bw0.y * __builtin_amdgcn_rcpf(1.0f + __expf(-(acc0[r] + bw0.x)));
                pA += bw1.y * __builtin_amdgcn_rcpf(1.0f + __expf(-(acc1[r] + bw1.x)));
            }
        }
        p += wgtA * pA;
        __syncthreads();                   // WAR: sA reads done before phase B writes
    }

    // =================== PHASE B ===========================================
    {
        #pragma unroll
        for (int q = 0; q < 4; ++q) {
            const bf16x8 gs = (q == 0) ? gB0 : (q == 1) ? gB1 : (q == 2) ? gB2 : gB3;
            union { bf16x8 v8; unsigned int u[4]; } gu, pk;
            gu.v8 = gs;
            const float4 hi0 = *(const float4*)&shpi[li][q * 8];
            const float4 hi1 = *(const float4*)&shpi[li][q * 8 + 4];
            const float4 hj0 = *(const float4*)&shpjB[lj][q * 8];
            const float4 hj1 = *(const float4*)&shpjB[lj][q * 8 + 4];
            float g0 = __uint_as_float(gu.u[0] << 16);
            float g1 = __uint_as_float(gu.u[0] & 0xffff0000u);
            float g2 = __uint_as_float(gu.u[1] << 16);
            float g3 = __uint_as_float(gu.u[1] & 0xffff0000u);
            float g4 = __uint_as_float(gu.u[2] << 16);
            float g5 = __uint_as_float(gu.u[2] & 0xffff0000u);
            float g6 = __uint_as_float(gu.u[3] << 16);
            float g7 = __uint_as_float(gu.u[3] & 0xffff0000u);
            float v0 = (hi0.x + hj0.x) * g0, v1 = (hi0.y + hj0.y) * g1;
            float v2 = (hi0.z + hj0.z) * g2, v3 = (hi0.w + hj0.w) * g3;
            float v4 = (hi1.x + hj1.x) * g4, v5 = (hi1.y + hj1.y) * g5;
            float v6 = (hi1.z + hj1.z) * g6, v7 = (hi1.w + hj1.w) * g7;
            float c0 = v0 * v0 * KB, c1 = v1 * v1 * KB, c2 = v2 * v2 * KB, c3 = v3 * v3 * KB;
            float c4 = v4 * v4 * KB, c5 = v5 * v5 * KB, c6 = v6 * v6 * KB, c7 = v7 * v7 * KB;
            pk.u[0] = ((__float_as_uint(c0) + 0x8000u) >> 16) | ((__float_as_uint(c1) + 0x8000u) & 0xffff0000u);
            pk.u[1] = ((__float_as_uint(c2) + 0x8000u) >> 16) | ((__float_as_uint(c3) + 0x8000u) & 0xffff0000u);
            pk.u[2] = ((__float_as_uint(c4) + 0x8000u) >> 16) | ((__float_as_uint(c5) + 0x8000u) & 0xffff0000u);
            pk.u[3] = ((__float_as_uint(c6) + 0x8000u) >> 16) | ((__float_as_uint(c7) + 0x8000u) & 0xffff0000u);
            *(bf16x8*)&sA[t * SASTR + (q ^ sw) * 8] = pk.v8;
        }
        __syncthreads();

        float pB = 0.f;
        #pragma unroll
        for (int rt = 0; rt < 4; ++rt) {
            const int row = w * 64 + rt * 16 + c0f;
            const int rq  = (lane >> 4) ^ ((row >> 3) & 3);
            bf16x8 afrag = *(const bf16x8*)&sA[row * SASTR + rq * 8];
            f32x4 acc0 = {0.f, 0.f, 0.f, 0.f};
            acc0 = __builtin_amdgcn_mfma_f32_16x16x32_bf16(afrag, bfrag0, acc0, 0, 0, 0);
            f32x4 acc1 = {0.f, 0.f, 0.f, 0.f};
            acc1 = __builtin_amdgcn_mfma_f32_16x16x32_bf16(afrag, bfrag1, acc1, 0, 0, 0);
            #pragma unroll
            for (int r = 0; r < 4; ++r) {
                pB += bw0.y * __builtin_amdgcn_rcpf(1.0f + __expf(-(acc0[r] + bw0.x)));
                pB += bw1.y * __builtin_amdgcn_rcpf(1.0f + __expf(-(acc1[r] + bw1.x)));
            }
        }
        p += wgtB * pB;
    }

    // block reduction (deterministic)
    float v = p;
    #pragma unroll
    for (int off = 32; off > 0; off >>= 1)
        v += __shfl_down(v, off);
    if (lane == 0) swave[w] = v;
    __syncthreads();
    if (t == 0)
        partials[b] = (swave[0] + swave[1]) + (swave[2] + swave[3]);
}

// ---- Kernel 3: final deterministic reduction -------------------------------
__global__ __launch_bounds__(256) void reduce_kernel(
    const float* __restrict__ partials, const float* __restrict__ b2,
    float* __restrict__ out)
{
    __shared__ float sm[256];
    const int t = threadIdx.x;
    float a = 0.f;
    for (int u = t; u < NBLK; u += 256) a += partials[u];
    sm[t] = a;
    __syncthreads();
    for (int off = 128; off > 0; off >>= 1) {
        if (t < off) sm[t] += sm[t + off];
        __syncthreads();
    }
    if (t == 0)
        out[0] = sm[0] + (float)N_ATOMS * (float)N_ATOMS * b2[0];
}

extern "C" void kernel_launch(void* const* d_in, const int* in_sizes, int n_in,
                              void* d_out, int out_size, void* d_ws, size_t ws_size,
                              hipStream_t stream) {
    const float* h      = (const float*)d_in[0];
    const float* x      = (const float*)d_in[1];
    const float* W_fc   = (const float*)d_in[2];
    const float* W_edge = (const float*)d_in[3];
    const float* means  = (const float*)d_in[4];
    const float* betas  = (const float*)d_in[5];
    const float* W1     = (const float*)d_in[6];
    const float* b1     = (const float*)d_in[7];
    const float* W2     = (const float*)d_in[8];
    const float* b2     = (const float*)d_in[9];
    float* out = (float*)d_out;

    char* base = (char*)d_ws;
    float*          ws_partials = (float*)base;                    // 1056 f @0
    float*          ws_hp       = (float*)(base + 10240);          // 32768 f
    unsigned short* ws_Gb       = (unsigned short*)(base + 141312);// 4096*32 bf16
    unsigned short* ws_Wp       = (unsigned short*)(base + 403456);// 1024 bf16
    float2*         ws_bw       = (float2*)(base + 405504);        // 32 float2
    int*            ws_tt       = (int*)(base + 405760);           // 1056 int

    prep_kernel<<<198, 256, 0, stream>>>(h, W_fc, W_edge, means, betas,
                                         W1, b1, W2, ws_hp, ws_Gb, ws_Wp,
                                         ws_bw, ws_tt);
    pair_kernel<<<NBLK, 256, 0, stream>>>(x, ws_hp, ws_Gb, ws_Wp, ws_bw,
                                          ws_tt, ws_partials);
    reduce_kernel<<<1, 256, 0, stream>>>(ws_partials, b2, out);
}